// Round 8
// baseline (125.756 us; speedup 1.0000x reference)
//
#include <hip/hip_runtime.h>
#include <hip/hip_bf16.h>

#define NTOKENS 500000
#define NSAMPLED 8192
#define NHID 256
#define BATCH 8192
#define LROW 8193  // 1 + NSAMPLED
#define OUT_TAIL ((size_t)BATCH * LROW)

typedef short s16x8 __attribute__((ext_vector_type(8)));
typedef float f32x4 __attribute__((ext_vector_type(4)));
typedef unsigned short u16;

// RNE float->bf16
static __device__ __forceinline__ u16 f2bf(float f) {
  unsigned u = __float_as_uint(f);
  return (u16)((u + 0x7fffu + ((u >> 16) & 1u)) >> 16);
}

static __device__ __forceinline__ s16x8 pack8(float4 v0, float4 v1) {
  s16x8 o;
  o[0] = (short)f2bf(v0.x); o[1] = (short)f2bf(v0.y);
  o[2] = (short)f2bf(v0.z); o[3] = (short)f2bf(v0.w);
  o[4] = (short)f2bf(v1.x); o[5] = (short)f2bf(v1.y);
  o[6] = (short)f2bf(v1.z); o[7] = (short)f2bf(v1.w);
  return o;
}

static __device__ __forceinline__ void gload_lds16(const void* g, void* l) {
  __builtin_amdgcn_global_load_lds(
      (const __attribute__((address_space(1))) void*)g,
      (__attribute__((address_space(3))) void*)l, 16, 0, 0);
}

// ---- fused prep: [0,1024) A->bf16 | [1024,2048) gather B->bf16 + colconst
//                  | [2048,4096) true logits + zero targets ----
__global__ void k_prep(const float* __restrict__ inputs, const int* __restrict__ labels,
                       const int* __restrict__ sample_ids, const float* __restrict__ tfreq,
                       const float* __restrict__ sfreq, const float* __restrict__ weight,
                       const float* __restrict__ bias, u16* __restrict__ outA,
                       u16* __restrict__ outB, float* __restrict__ colconst,
                       float* __restrict__ out) {
  int bid = blockIdx.x;
  int t = threadIdx.x;
  if (bid < 1024) {                       // inputs fp32 -> bf16 [BATCH][NHID]
    size_t idx = ((size_t)bid * 256 + t) * 8;
    const float4* p = (const float4*)(inputs + idx);
    *(s16x8*)(outA + idx) = pack8(p[0], p[1]);
  } else if (bid < 2048) {                // gather weight[sample_ids] -> bf16; colconst
    int r = (bid - 1024) * 8 + (t >> 5);
    int l = t & 31;
    int s = sample_ids[r];
    const float* src = weight + (size_t)s * NHID + l * 8;
    *(s16x8*)(outB + (size_t)r * NHID + l * 8) =
        pack8(((const float4*)src)[0], ((const float4*)src)[1]);
    if (l == 0) colconst[r] = bias[s] - sfreq[r];
  } else {                                // true logits (col 0) + int32 zeros tail
    int bb = bid - 2048;
    int w = t >> 6, lane = t & 63;
    int b = bb * 4 + w;
    int lab = labels[b];
    const float4 x = *(const float4*)(inputs + (size_t)b * NHID + lane * 4);
    const float4 ww = *(const float4*)(weight + (size_t)lab * NHID + lane * 4);
    float s = x.x * ww.x + x.y * ww.y + x.z * ww.z + x.w * ww.w;
    #pragma unroll
    for (int off = 32; off; off >>= 1) s += __shfl_down(s, off, 64);
    if (lane == 0) out[(size_t)b * LROW] = s + bias[lab] - tfreq[b];
    int tid = bb * 256 + t;
    if (tid < BATCH) out[OUT_TAIL + tid] = 0.0f;
  }
}

// ---- GEMM: C[b][s] = sum_k A[b][k]*B[s][k] + colconst[s] ----
// 128x256 tile, 512 thr = 8 waves of 32x128, BK=64 x4, 2 blocks/CU.
// LDS-transpose epilogue -> 16B-aligned f32x4 FULL-LINE stores, NON-TEMPORAL:
// complete 128B lines stream to HBM without allocating in L2 (no RMW since
// lines are whole — r3's NT failure was partial 64B sectors), so the A/B
// panels stay L2-resident and stage reads stop falling to L3 (the write
// stream was evicting them: the real ~25us cost, r6 analysis).
__global__ __launch_bounds__(512, 4) void k_gemm(const u16* __restrict__ A,
                                                 const u16* __restrict__ B,
                                                 const float* __restrict__ colconst,
                                                 float* __restrict__ out) {
  // main phase: lA 16KB + lB 32KB; epilogue aliases 8 waves x 8448B = 67.6KB
  __shared__ __align__(16) char smem[67584];
  u16* lA = (u16*)smem;             // [128 rows][64 k], XOR-swizzled chunks
  u16* lB = (u16*)(smem + 16384);   // [256 cols][64 k]
  int t = threadIdx.x;
  int lane = t & 63;
  int w = t >> 6;               // 0..7
  // XCD rectangle: grid 64 rowtiles x 32 coltiles; per XCD 16x16 rectangle.
  int bid = blockIdx.x;
  int xcd = bid & 7, i = bid >> 3;        // i in 0..255
  int brow = (xcd >> 1) * 16 + (i >> 4);  // 0..63 (128-row tiles)
  int bcol = (xcd & 1) * 16 + (i & 15);   // 0..31 (256-col tiles)
  int wr = w >> 1, wc = w & 1;            // wave: rows wr*32+, cols wc*128+
  const int l15 = lane & 15;
  const int lhi = lane >> 4;

  f32x4 acc[2][8];
  #pragma unroll
  for (int a = 0; a < 2; ++a)
    #pragma unroll
    for (int b = 0; b < 8; ++b) acc[a][b] = (f32x4){0.f, 0.f, 0.f, 0.f};

  const u16* Abase = A + (size_t)brow * 128 * NHID;
  const u16* Bbase = B + (size_t)bcol * 256 * NHID;

  for (int kt = 0; kt < 4; ++kt) {
    #pragma unroll
    for (int j = 0; j < 2; ++j) {
      int chunk = w * 128 + j * 64 + lane;
      int row = chunk >> 3;
      int cs = (chunk & 7) ^ (row & 7);
      gload_lds16(Abase + (size_t)row * NHID + kt * 64 + cs * 8,
                  lA + (size_t)(w * 128 + j * 64) * 8);
    }
    #pragma unroll
    for (int j = 0; j < 4; ++j) {
      int chunk = w * 256 + j * 64 + lane;
      int row = chunk >> 3;
      int cs = (chunk & 7) ^ (row & 7);
      gload_lds16(Bbase + (size_t)row * NHID + kt * 64 + cs * 8,
                  lB + (size_t)(w * 256 + j * 64) * 8);
    }
    __syncthreads();
    #pragma unroll
    for (int ks = 0; ks < 2; ++ks) {
      int kc = ks * 4 + lhi;
      s16x8 af[2];
      #pragma unroll
      for (int mi = 0; mi < 2; ++mi) {
        int row = wr * 32 + mi * 16 + l15;
        af[mi] = *(const s16x8*)(lA + row * 64 + ((kc ^ (row & 7)) * 8));
      }
      #pragma unroll
      for (int ni = 0; ni < 8; ++ni) {
        int row = wc * 128 + ni * 16 + l15;
        s16x8 bf = *(const s16x8*)(lB + row * 64 + ((kc ^ (row & 7)) * 8));
        #pragma unroll
        for (int mi = 0; mi < 2; ++mi)
          acc[mi][ni] = __builtin_amdgcn_mfma_f32_16x16x32_bf16(af[mi], bf, acc[mi][ni], 0, 0, 0);
      }
    }
    __syncthreads();  // after last kt: safe to alias smem in the epilogue
  }

  // ---- LDS-transpose epilogue ----
  float* epi = (float*)smem + (size_t)w * 2112;  // private: 16 rows x 132 floats
  int grow0 = brow * 128 + wr * 32;
  int gcol0 = bcol * 256 + wc * 128;
  float cc[8];
  #pragma unroll
  for (int ni = 0; ni < 8; ++ni) cc[ni] = colconst[gcol0 + ni * 16 + l15];

  #pragma unroll
  for (int mi = 0; mi < 2; ++mi) {
    // write phase: slot (cloc - s) mod 128 holds global col gcol0 + cloc
    #pragma unroll
    for (int ni = 0; ni < 8; ++ni) {
      #pragma unroll
      for (int r = 0; r < 4; ++r) {
        int rloc = lhi * 4 + r;
        int R = grow0 + mi * 16 + rloc;
        int s = (~R) & 3;
        int cloc = ni * 16 + l15;
        epi[rloc * 132 + ((cloc - s) & 127)] = acc[mi][ni][r] + cc[ni];
      }
    }
    __syncthreads();
    // aligned f32x4 phase: slot i holds col i+s -> NON-TEMPORAL full-line
    // stores (16 consecutive lanes = 256B contiguous = 2 whole 128B lines).
    #pragma unroll
    for (int j = 0; j < 8; ++j) {
      int rloc = (j & 3) * 4 + lhi;
      int cg = (j >> 2) * 16 + l15;
      int R = grow0 + mi * 16 + rloc;
      int s = (~R) & 3;
      f32x4 v = *(const f32x4*)(epi + rloc * 132 + cg * 4);
      if (cg < 31 || s == 0)
        __builtin_nontemporal_store(v, (f32x4*)(out + (size_t)R * LROW + 1 + gcol0 + cg * 4 + s));
    }
    // ragged edges (<=3% of bytes): PLAIN dword stores so L2 merges them.
    {
      int rloc = lane >> 2;
      int e = lane & 3;
      int R = grow0 + mi * 16 + rloc;
      int s = (~R) & 3;
      if (s > 0) {
        int col = (e < s) ? e : (124 + e);
        int lidx = (e < s) ? (128 - s + e) : (col - s);
        out[(size_t)R * LROW + 1 + gcol0 + col] = epi[rloc * 132 + lidx];
      }
    }
    __syncthreads();
  }
}

extern "C" void kernel_launch(void* const* d_in, const int* in_sizes, int n_in,
                              void* d_out, int out_size, void* d_ws, size_t ws_size,
                              hipStream_t stream) {
  const float* inputs          = (const float*)d_in[0];
  const int*   labels          = (const int*)d_in[1];
  const int*   sample_ids      = (const int*)d_in[2];
  const float* true_log_freq   = (const float*)d_in[3];
  const float* sample_log_freq = (const float*)d_in[4];
  const float* weight          = (const float*)d_in[5];
  const float* bias            = (const float*)d_in[6];
  float* out = (float*)d_out;

  u16* wsA = (u16*)d_ws;                                      // 4 MB
  u16* wsB = wsA + (size_t)BATCH * NHID;                      // 4 MB
  float* colconst = (float*)(wsB + (size_t)NSAMPLED * NHID);  // 32 KB

  hipLaunchKernelGGL(k_prep, dim3(4096), dim3(256), 0, stream,
                     inputs, labels, sample_ids, true_log_freq, sample_log_freq,
                     weight, bias, wsA, wsB, colconst, out);
  hipLaunchKernelGGL(k_gemm, dim3(2048), dim3(512), 0, stream, wsA, wsB, colconst, out);
}

// Round 9
// 100.773 us; speedup vs baseline: 1.2479x; 1.2479x over previous
//
#include <hip/hip_runtime.h>
#include <hip/hip_bf16.h>

#define NTOKENS 500000
#define NSAMPLED 8192
#define NHID 256
#define BATCH 8192
#define LROW 8193  // 1 + NSAMPLED
#define OUT_TAIL ((size_t)BATCH * LROW)

typedef short s16x8 __attribute__((ext_vector_type(8)));
typedef float f32x4 __attribute__((ext_vector_type(4)));
typedef unsigned short u16;

// RNE float->bf16
static __device__ __forceinline__ u16 f2bf(float f) {
  unsigned u = __float_as_uint(f);
  return (u16)((u + 0x7fffu + ((u >> 16) & 1u)) >> 16);
}

static __device__ __forceinline__ s16x8 pack8(float4 v0, float4 v1) {
  s16x8 o;
  o[0] = (short)f2bf(v0.x); o[1] = (short)f2bf(v0.y);
  o[2] = (short)f2bf(v0.z); o[3] = (short)f2bf(v0.w);
  o[4] = (short)f2bf(v1.x); o[5] = (short)f2bf(v1.y);
  o[6] = (short)f2bf(v1.z); o[7] = (short)f2bf(v1.w);
  return o;
}

static __device__ __forceinline__ void gload_lds16(const void* g, void* l) {
  __builtin_amdgcn_global_load_lds(
      (const __attribute__((address_space(1))) void*)g,
      (__attribute__((address_space(3))) void*)l, 16, 0, 0);
}

// ---- fused prep: [0,1024) A->bf16 | [1024,2048) gather B->bf16 + colconst
//                  | [2048,4096) true logits + zero targets ----
__global__ void k_prep(const float* __restrict__ inputs, const int* __restrict__ labels,
                       const int* __restrict__ sample_ids, const float* __restrict__ tfreq,
                       const float* __restrict__ sfreq, const float* __restrict__ weight,
                       const float* __restrict__ bias, u16* __restrict__ outA,
                       u16* __restrict__ outB, float* __restrict__ colconst,
                       float* __restrict__ out) {
  int bid = blockIdx.x;
  int t = threadIdx.x;
  if (bid < 1024) {                       // inputs fp32 -> bf16 [BATCH][NHID]
    size_t idx = ((size_t)bid * 256 + t) * 8;
    const float4* p = (const float4*)(inputs + idx);
    *(s16x8*)(outA + idx) = pack8(p[0], p[1]);
  } else if (bid < 2048) {                // gather weight[sample_ids] -> bf16; colconst
    int r = (bid - 1024) * 8 + (t >> 5);
    int l = t & 31;
    int s = sample_ids[r];
    const float* src = weight + (size_t)s * NHID + l * 8;
    *(s16x8*)(outB + (size_t)r * NHID + l * 8) =
        pack8(((const float4*)src)[0], ((const float4*)src)[1]);
    if (l == 0) colconst[r] = bias[s] - sfreq[r];
  } else {                                // true logits (col 0) + int32 zeros tail
    int bb = bid - 2048;
    int w = t >> 6, lane = t & 63;
    int b = bb * 4 + w;
    int lab = labels[b];
    const float4 x = *(const float4*)(inputs + (size_t)b * NHID + lane * 4);
    const float4 ww = *(const float4*)(weight + (size_t)lab * NHID + lane * 4);
    float s = x.x * ww.x + x.y * ww.y + x.z * ww.z + x.w * ww.w;
    #pragma unroll
    for (int off = 32; off; off >>= 1) s += __shfl_down(s, off, 64);
    if (lane == 0) out[(size_t)b * LROW] = s + bias[lab] - tfreq[b];
    int tid = bb * 256 + t;
    if (tid < BATCH) out[OUT_TAIL + tid] = 0.0f;
  }
}

// ---- stream-and-store GEMM: C[b][s] = sum_k A[b][k]*B[s][k] + colconst[s] ----
// Block = 32-row stripe x 4096-col slab, chunked 32x of 128 cols. Full K=256
// per chunk -> acc completes -> store IMMEDIATELY. Stores spread over 32
// phases/block x 2 blocks/CU => dense write stream (r5's gap was store duty
// cycle ~45%: terminal epilogue bursts). A (16KB) staged once; B chunk 64KB
// single-buffered; LDS 80KB/block, 2 blocks/CU. Plain dword scatter stores
// (NT banned: r3/r8; store instruction shape irrelevant: r6).
__global__ __launch_bounds__(512, 4) void k_gemm(const u16* __restrict__ A,
                                                 const u16* __restrict__ B,
                                                 const float* __restrict__ colconst,
                                                 float* __restrict__ out) {
  __shared__ u16 lA[32 * 256];    // 16KB, [row][k] XOR-swizzled 16B chunks
  __shared__ u16 lB[128 * 256];   // 64KB, [col][k]
  int t = threadIdx.x;
  int lane = t & 63;
  int w = t >> 6;                 // 0..7
  const int l15 = lane & 15;
  const int lhi = lane >> 4;
  // XCD affinity: 2 col-slabs (4096 cols), 4 XCDs each; per XCD: B slab 2MB
  // + 64 A-rowtiles 1MB = 3MB < 4MiB L2. bid&7 = XCD (round-robin dispatch).
  int bid = blockIdx.x;
  int xcd = bid & 7, i = bid >> 3;   // i 0..63
  int slab = xcd >> 2;               // 0..1
  int brow = (xcd & 3) * 64 + i;     // 0..255 (32-row stripes)
  int wr = w >> 2;                   // 0..1: rows wr*16
  int wc = w & 3;                    // 0..3: cols wc*32

  // stage A once: 1024 16B-chunks, 2 per thread
  #pragma unroll
  for (int j = 0; j < 2; ++j) {
    int idx = (w * 2 + j) * 64 + lane;
    int row = idx >> 5, c = idx & 31;
    int cs = c ^ (row & 7);
    gload_lds16(A + (size_t)(brow * 32 + row) * NHID + cs * 8, lA + (w * 2 + j) * 512);
  }

  for (int ch = 0; ch < 32; ++ch) {
    // stage B chunk: 128 cols, 4096 16B-chunks, 8 per thread
    int colbase = slab * 4096 + ch * 128;
    #pragma unroll
    for (int j = 0; j < 8; ++j) {
      int idx = (w * 8 + j) * 64 + lane;
      int col = idx >> 5, c = idx & 31;
      int cs = c ^ (col & 7);
      gload_lds16(B + (size_t)(colbase + col) * NHID + cs * 8, lB + (w * 8 + j) * 512);
    }
    __syncthreads();  // B (and A on ch=0) resident

    f32x4 acc[2];
    acc[0] = (f32x4){0.f, 0.f, 0.f, 0.f};
    acc[1] = (f32x4){0.f, 0.f, 0.f, 0.f};
    #pragma unroll
    for (int ks = 0; ks < 8; ++ks) {
      int c = ks * 4 + lhi;            // 16B-chunk index along K
      int ra = wr * 16 + l15;
      s16x8 af = *(const s16x8*)(lA + ra * 256 + ((c ^ (ra & 7)) * 8));
      #pragma unroll
      for (int ni = 0; ni < 2; ++ni) {
        int rb = wc * 32 + ni * 16 + l15;
        s16x8 bf = *(const s16x8*)(lB + rb * 256 + ((c ^ (rb & 7)) * 8));
        acc[ni] = __builtin_amdgcn_mfma_f32_16x16x32_bf16(af, bf, acc[ni], 0, 0, 0);
      }
    }

    // store this chunk now: 32 rows x 512B segments (dword scatter, proven)
    int gcol0 = colbase + wc * 32;
    float cc[2];
    #pragma unroll
    for (int ni = 0; ni < 2; ++ni) cc[ni] = colconst[gcol0 + ni * 16 + l15];
    #pragma unroll
    for (int r = 0; r < 4; ++r) {
      size_t rbase = (size_t)(brow * 32 + wr * 16 + lhi * 4 + r) * LROW + 1;
      #pragma unroll
      for (int ni = 0; ni < 2; ++ni)
        out[rbase + gcol0 + ni * 16 + l15] = acc[ni][r] + cc[ni];
    }
    __syncthreads();  // all waves done reading lB before next stage
  }
}

extern "C" void kernel_launch(void* const* d_in, const int* in_sizes, int n_in,
                              void* d_out, int out_size, void* d_ws, size_t ws_size,
                              hipStream_t stream) {
  const float* inputs          = (const float*)d_in[0];
  const int*   labels          = (const int*)d_in[1];
  const int*   sample_ids      = (const int*)d_in[2];
  const float* true_log_freq   = (const float*)d_in[3];
  const float* sample_log_freq = (const float*)d_in[4];
  const float* weight          = (const float*)d_in[5];
  const float* bias            = (const float*)d_in[6];
  float* out = (float*)d_out;

  u16* wsA = (u16*)d_ws;                                      // 4 MB
  u16* wsB = wsA + (size_t)BATCH * NHID;                      // 4 MB
  float* colconst = (float*)(wsB + (size_t)NSAMPLED * NHID);  // 32 KB

  hipLaunchKernelGGL(k_prep, dim3(4096), dim3(256), 0, stream,
                     inputs, labels, sample_ids, true_log_freq, sample_log_freq,
                     weight, bias, wsA, wsB, colconst, out);
  hipLaunchKernelGGL(k_gemm, dim3(512), dim3(512), 0, stream, wsA, wsB, colconst, out);
}

// Round 10
// 86.230 us; speedup vs baseline: 1.4584x; 1.1686x over previous
//
#include <hip/hip_runtime.h>
#include <hip/hip_bf16.h>

#define NTOKENS 500000
#define NSAMPLED 8192
#define NHID 256
#define BATCH 8192
#define LROW 8193  // 1 + NSAMPLED
#define OUT_TAIL ((size_t)BATCH * LROW)

typedef short s16x8 __attribute__((ext_vector_type(8)));
typedef float f32x4 __attribute__((ext_vector_type(4)));
typedef unsigned short u16;

// RNE float->bf16
static __device__ __forceinline__ u16 f2bf(float f) {
  unsigned u = __float_as_uint(f);
  return (u16)((u + 0x7fffu + ((u >> 16) & 1u)) >> 16);
}

static __device__ __forceinline__ s16x8 pack8(float4 v0, float4 v1) {
  s16x8 o;
  o[0] = (short)f2bf(v0.x); o[1] = (short)f2bf(v0.y);
  o[2] = (short)f2bf(v0.z); o[3] = (short)f2bf(v0.w);
  o[4] = (short)f2bf(v1.x); o[5] = (short)f2bf(v1.y);
  o[6] = (short)f2bf(v1.z); o[7] = (short)f2bf(v1.w);
  return o;
}

static __device__ __forceinline__ void gload_lds16(const void* g, void* l) {
  __builtin_amdgcn_global_load_lds(
      (const __attribute__((address_space(1))) void*)g,
      (__attribute__((address_space(3))) void*)l, 16, 0, 0);
}

// ---- fused prep: [0,1024) A->bf16 | [1024,2048) gather B->bf16 + colconst
//                  | [2048,4096) true logits + zero targets ----
__global__ void k_prep(const float* __restrict__ inputs, const int* __restrict__ labels,
                       const int* __restrict__ sample_ids, const float* __restrict__ tfreq,
                       const float* __restrict__ sfreq, const float* __restrict__ weight,
                       const float* __restrict__ bias, u16* __restrict__ outA,
                       u16* __restrict__ outB, float* __restrict__ colconst,
                       float* __restrict__ out) {
  int bid = blockIdx.x;
  int t = threadIdx.x;
  if (bid < 1024) {                       // inputs fp32 -> bf16 [BATCH][NHID]
    size_t idx = ((size_t)bid * 256 + t) * 8;
    const float4* p = (const float4*)(inputs + idx);
    *(s16x8*)(outA + idx) = pack8(p[0], p[1]);
  } else if (bid < 2048) {                // gather weight[sample_ids] -> bf16; colconst
    int r = (bid - 1024) * 8 + (t >> 5);
    int l = t & 31;
    int s = sample_ids[r];
    const float* src = weight + (size_t)s * NHID + l * 8;
    *(s16x8*)(outB + (size_t)r * NHID + l * 8) =
        pack8(((const float4*)src)[0], ((const float4*)src)[1]);
    if (l == 0) colconst[r] = bias[s] - sfreq[r];
  } else {                                // true logits (col 0) + int32 zeros tail
    int bb = bid - 2048;
    int w = t >> 6, lane = t & 63;
    int b = bb * 4 + w;
    int lab = labels[b];
    const float4 x = *(const float4*)(inputs + (size_t)b * NHID + lane * 4);
    const float4 ww = *(const float4*)(weight + (size_t)lab * NHID + lane * 4);
    float s = x.x * ww.x + x.y * ww.y + x.z * ww.z + x.w * ww.w;
    #pragma unroll
    for (int off = 32; off; off >>= 1) s += __shfl_down(s, off, 64);
    if (lane == 0) out[(size_t)b * LROW] = s + bias[lab] - tfreq[b];
    int tid = bb * 256 + t;
    if (tid < BATCH) out[OUT_TAIL + tid] = 0.0f;
  }
}

// ---- GEMM: C[b][s] = sum_k A[b][k]*B[s][k] + colconst[s] ----
// r5 structure (best known: 85.6us): 128x256 tile, 512 thr = 8 waves of
// 32x128, BK=64 x4, single-buffered 48KB LDS, dword-scatter epilogue.
// ONE change: PLAIN ROW-MAJOR bid mapping (brow=bid>>5, bcol=bid&31).
// Round-robin dispatch then puts all 32 col-tiles of a row-stripe in flight
// simultaneously -> adjacent 1KB row-segments are written in the same time
// window -> DRAM pages fully covered (near-sequential write behavior).
// The r2-r9 "XCD-aware" rectangle optimized READ locality but scattered
// adjacent WRITES far apart in time — never A/B-tested until now.
__global__ __launch_bounds__(512, 4) void k_gemm(const u16* __restrict__ A,
                                                 const u16* __restrict__ B,
                                                 const float* __restrict__ colconst,
                                                 float* __restrict__ out) {
  __shared__ u16 lA[128 * 64];  // [row 0..127][k 0..63], XOR-swizzled chunks
  __shared__ u16 lB[256 * 64];  // [col 0..255][k 0..63]
  int t = threadIdx.x;
  int lane = t & 63;
  int w = t >> 6;               // 0..7
  int bid = blockIdx.x;
  int brow = bid >> 5;          // 0..63 (128-row tiles) — row-major mapping
  int bcol = bid & 31;          // 0..31 (256-col tiles)
  int wr = w >> 1, wc = w & 1;  // wave: rows wr*32+, cols wc*128+
  const int l15 = lane & 15;
  const int lhi = lane >> 4;

  f32x4 acc[2][8];
  #pragma unroll
  for (int a = 0; a < 2; ++a)
    #pragma unroll
    for (int b = 0; b < 8; ++b) acc[a][b] = (f32x4){0.f, 0.f, 0.f, 0.f};

  const u16* Abase = A + (size_t)brow * 128 * NHID;
  const u16* Bbase = B + (size_t)bcol * 256 * NHID;

  for (int kt = 0; kt < 4; ++kt) {
    #pragma unroll
    for (int j = 0; j < 2; ++j) {
      int chunk = w * 128 + j * 64 + lane;
      int row = chunk >> 3;
      int cs = (chunk & 7) ^ (row & 7);
      gload_lds16(Abase + (size_t)row * NHID + kt * 64 + cs * 8,
                  lA + (size_t)(w * 128 + j * 64) * 8);
    }
    #pragma unroll
    for (int j = 0; j < 4; ++j) {
      int chunk = w * 256 + j * 64 + lane;
      int row = chunk >> 3;
      int cs = (chunk & 7) ^ (row & 7);
      gload_lds16(Bbase + (size_t)row * NHID + kt * 64 + cs * 8,
                  lB + (size_t)(w * 256 + j * 64) * 8);
    }
    __syncthreads();
    #pragma unroll
    for (int ks = 0; ks < 2; ++ks) {
      int kc = ks * 4 + lhi;
      s16x8 af[2];
      #pragma unroll
      for (int mi = 0; mi < 2; ++mi) {
        int row = wr * 32 + mi * 16 + l15;
        af[mi] = *(const s16x8*)(lA + row * 64 + ((kc ^ (row & 7)) * 8));
      }
      #pragma unroll
      for (int ni = 0; ni < 8; ++ni) {
        int row = wc * 128 + ni * 16 + l15;
        s16x8 bf = *(const s16x8*)(lB + row * 64 + ((kc ^ (row & 7)) * 8));
        #pragma unroll
        for (int mi = 0; mi < 2; ++mi)
          acc[mi][ni] = __builtin_amdgcn_mfma_f32_16x16x32_bf16(af[mi], bf, acc[mi][ni], 0, 0, 0);
      }
    }
    __syncthreads();
  }

  // epilogue: + colconst, plain dword scatter stores (proven best shape)
  int grow0 = brow * 128 + wr * 32;
  int gcol0 = bcol * 256 + wc * 128;
  float cc[8];
  #pragma unroll
  for (int ni = 0; ni < 8; ++ni) cc[ni] = colconst[gcol0 + ni * 16 + l15];
  #pragma unroll
  for (int mi = 0; mi < 2; ++mi) {
    #pragma unroll
    for (int r = 0; r < 4; ++r) {
      size_t rbase = (size_t)(grow0 + mi * 16 + lhi * 4 + r) * LROW + 1;
      #pragma unroll
      for (int ni = 0; ni < 8; ++ni)
        out[rbase + gcol0 + ni * 16 + l15] = acc[mi][ni][r] + cc[ni];
    }
  }
}

extern "C" void kernel_launch(void* const* d_in, const int* in_sizes, int n_in,
                              void* d_out, int out_size, void* d_ws, size_t ws_size,
                              hipStream_t stream) {
  const float* inputs          = (const float*)d_in[0];
  const int*   labels          = (const int*)d_in[1];
  const int*   sample_ids      = (const int*)d_in[2];
  const float* true_log_freq   = (const float*)d_in[3];
  const float* sample_log_freq = (const float*)d_in[4];
  const float* weight          = (const float*)d_in[5];
  const float* bias            = (const float*)d_in[6];
  float* out = (float*)d_out;

  u16* wsA = (u16*)d_ws;                                      // 4 MB
  u16* wsB = wsA + (size_t)BATCH * NHID;                      // 4 MB
  float* colconst = (float*)(wsB + (size_t)NSAMPLED * NHID);  // 32 KB

  hipLaunchKernelGGL(k_prep, dim3(4096), dim3(256), 0, stream,
                     inputs, labels, sample_ids, true_log_freq, sample_log_freq,
                     weight, bias, wsA, wsB, colconst, out);
  hipLaunchKernelGGL(k_gemm, dim3(2048), dim3(512), 0, stream, wsA, wsB, colconst, out);
}